// Round 3
// 539.308 us; speedup vs baseline: 1.1774x; 1.1774x over previous
//
#include <hip/hip_runtime.h>
#include <math.h>

// B=8, Q=4096, C=256, H=8, D=32, L=4, P=4; levels 128/64/32/16 squared.
// R8: R7 + NaN fix. 8-byte sinfo per point (signed i00 + bf16 X0,X1 + fixed wy +
// validity). NaN root cause: unclamped taps read outside vbuf where garbage bytes
// can decode to bf16 NaN/Inf; 0*NaN = NaN. Fix: (1) fully-invalid points emit
// pk={0,0} in K1, bounding stray reads to +-(Wl+1) rows; (2) 128KB zeroed guard
// zones before/after vbuf (cleared by prep blocks 56..63 each launch).
// ws layout (bytes):
//  sinfo uint2 @0 (33,554,432)
//  guard_lo @33,554,432 (131,072)
//  vbuf bf16 @33,685,504 (89,128,960: 8 batches x 21760 x 256) -> ends 122,814,464
//  guard_hi @122,814,464 (131,072)
//  preb bf16 @122,945,536 (16,777,216) -> ends 139,722,752
//  wqT bf16[384][256] @139,722,752 | wv bf16[4][256][256] @139,919,360
//  woT bf16[256][256] @140,443,648 -> end 140,574,720 (< proven 148,701,184)

typedef __attribute__((ext_vector_type(8))) short short8_t;
typedef __attribute__((ext_vector_type(4))) short short4_t;
typedef __attribute__((ext_vector_type(4))) float floatx4;

__device__ __forceinline__ float bf2f(unsigned short u) {
    return __uint_as_float(((unsigned int)u) << 16);
}
__device__ __forceinline__ unsigned short f2bf(float f) {
    unsigned int x = __float_as_uint(f);
    unsigned int r = x + 0x7fffu + ((x >> 16) & 1u);
    return (unsigned short)(r >> 16);
}

#define MFMA16(a, b, c) __builtin_amdgcn_mfma_f32_16x16x32_bf16((a), (b), (c), 0, 0, 0)
#define LPAD 40  // LDS row stride in shorts: 80 B = 16B-aligned frags, ~2-way banks (free)

// ---------------- K0: weight prep: cast + transpose to bf16; blocks 56..63 zero guards
__global__ __launch_bounds__(256) void prep_kernel(
    const float* __restrict__ W_off, const float* __restrict__ W_attn,
    const float* __restrict__ Wv0, const float* __restrict__ Wv1,
    const float* __restrict__ Wv2, const float* __restrict__ Wv3,
    const float* __restrict__ W_out,
    unsigned short* __restrict__ wq,
    unsigned short* __restrict__ wv,
    unsigned short* __restrict__ wo,
    uint4* __restrict__ guard_lo,
    uint4* __restrict__ guard_hi)
{
    const int t = threadIdx.x;
    const int blk = blockIdx.x;
    if (blk < 40) {
        __shared__ float tile[64][65];
        int n0, c0, ncols, nbase;
        const float* src;
        unsigned short* dst;
        if (blk < 24) {
            int tt = blk; n0 = (tt >> 2) * 64; c0 = (tt & 3) * 64;
            if (n0 < 256) { src = W_off; ncols = 256; nbase = n0; }
            else          { src = W_attn; ncols = 128; nbase = n0 - 256; }
            dst = wq;
        } else {
            int tt = blk - 24; n0 = (tt >> 2) * 64; c0 = (tt & 3) * 64;
            src = W_out; ncols = 256; nbase = n0; dst = wo;
        }
        for (int i = 0; i < 4; ++i) {
            int idx = i * 256 + t; int c = idx >> 4, n4 = idx & 15;
            float4 v = *(const float4*)&src[(long)(c0 + c) * ncols + nbase + 4 * n4];
            tile[4 * n4 + 0][c] = v.x; tile[4 * n4 + 1][c] = v.y;
            tile[4 * n4 + 2][c] = v.z; tile[4 * n4 + 3][c] = v.w;
        }
        __syncthreads();
        for (int i = 0; i < 4; ++i) {
            int idx = i * 256 + t; int n = idx >> 4, cg = idx & 15;
            short4_t pk;
            pk[0] = (short)f2bf(tile[n][4 * cg + 0]);
            pk[1] = (short)f2bf(tile[n][4 * cg + 1]);
            pk[2] = (short)f2bf(tile[n][4 * cg + 2]);
            pk[3] = (short)f2bf(tile[n][4 * cg + 3]);
            *(short4_t*)&dst[(long)(n0 + n) * 256 + c0 + 4 * cg] = pk;
        }
    } else if (blk < 56) {
        long g0 = (long)(blk - 40) * 16384;
        for (int i = 0; i < 16; ++i) {
            long e = g0 + (long)(i * 256 + t) * 4;
            int l = (int)(e >> 16); int off = (int)(e & 65535);
            const float* s = (l == 0) ? Wv0 : (l == 1) ? Wv1 : (l == 2) ? Wv2 : Wv3;
            float4 v = *(const float4*)&s[off];
            short4_t pk;
            pk[0] = (short)f2bf(v.x); pk[1] = (short)f2bf(v.y);
            pk[2] = (short)f2bf(v.z); pk[3] = (short)f2bf(v.w);
            *(short4_t*)&wv[e] = pk;
        }
    } else {
        // zero 128KB guard zones: 4 blocks each, 32768 B/block = 8 iters x 4096 B
        uint4 z = {0u, 0u, 0u, 0u};
        int sub = (blk - 56) & 3;
        uint4* g = (blk < 60) ? guard_lo : guard_hi;
        g += (long)sub * 2048 + t;   // uint4 units: 32768/16 = 2048 per block
        for (int i = 0; i < 8; ++i) g[i * 256] = z;
    }
}

// ---------------- K1: qproj MFMA. M=32768, N=384, K=256.
// Fused epilogue: softmax (staged to LDS) -> tanh -> bilinear setup packed 8B/point.
// sinfo encoding: word0 = u16(i00 signed) | f2bf(X0)<<16
//                 word1 = f2bf(X1) | (wy14 | vy0<<14 | vy1<<15)<<16
// X0=a*(1-wx)*vx0, X1=a*wx*vx1, i00 = rowb + y0*Wl + x0 (unclamped). Fully-invalid
// points (no valid x tap or no valid y tap) emit {0,0} so K3 reads stay in-bounds.
__global__ __launch_bounds__(256) void qproj_mfma(
    const float* __restrict__ query, const float* __restrict__ refp,
    const unsigned short* __restrict__ wq,
    const float* __restrict__ b_off, const float* __restrict__ b_attn,
    uint2* __restrict__ sinfo)
{
    __shared__ __align__(16) char smem[35840];
    unsigned short* aT = (unsigned short*)smem;            // 64*LPAD shorts = 5120 B
    unsigned short* bT = (unsigned short*)(smem + 5120);   // 384*LPAD shorts = 30720 B
    float* sA = (float*)smem;                              // reused: 64*128 f32 = 32768 B

    const int t = threadIdx.x;
    const int r0 = blockIdx.x * 64;
    const int w = t >> 6, lane = t & 63, quad = lane >> 4, l15 = lane & 15;

    floatx4 acc[24];
#pragma unroll
    for (int i = 0; i < 24; ++i) acc[i] = (floatx4){0.f, 0.f, 0.f, 0.f};

    for (int k0 = 0; k0 < 256; k0 += 32) {
        __syncthreads();
        for (int i = 0; i < 2; ++i) {  // A: query 64x32 fp32 -> bf16 (512 float4)
            int idx = i * 256 + t; int row = idx >> 3, kq = idx & 7;
            float4 v = *(const float4*)&query[(long)(r0 + row) * 256 + k0 + 4 * kq];
            short4_t pk;
            pk[0] = (short)f2bf(v.x); pk[1] = (short)f2bf(v.y);
            pk[2] = (short)f2bf(v.z); pk[3] = (short)f2bf(v.w);
            *(short4_t*)&aT[row * LPAD + 4 * kq] = pk;
        }
        for (int i = 0; i < 6; ++i) {  // B: wqT 384x32 bf16 (1536 uint4)
            int idx = i * 256 + t; int n = idx >> 2, kq = idx & 3;
            uint4 v = *(const uint4*)&wq[(long)n * 256 + k0 + 8 * kq];
            *(uint4*)&bT[n * LPAD + 8 * kq] = v;
        }
        __syncthreads();
        short8_t a8 = *(const short8_t*)&aT[(16 * w + l15) * LPAD + 8 * quad];
#pragma unroll
        for (int j = 0; j < 24; ++j) {
            short8_t b8 = *(const short8_t*)&bT[(16 * j + l15) * LPAD + 8 * quad];
            acc[j] = MFMA16(a8, b8, acc[j]);
        }
    }

    const int row = 16 * w + 4 * quad;          // block-local row base (D row = row+g)
    const int rbase = r0 + row;

    // ---- softmax first; stage a = e/s into LDS (overwrites aT/bT after sync)
    __syncthreads();
#pragma unroll
    for (int j = 16; j < 24; ++j) {
        int h = j - 16;
        float bias = b_attn[16 * h + l15];
#pragma unroll
        for (int g = 0; g < 4; ++g) {
            float v = acc[j][g] + bias;
            float m = v;
            m = fmaxf(m, __shfl_xor(m, 1)); m = fmaxf(m, __shfl_xor(m, 2));
            m = fmaxf(m, __shfl_xor(m, 4)); m = fmaxf(m, __shfl_xor(m, 8));
            float e = __expf(v - m);
            float s = e;
            s += __shfl_xor(s, 1); s += __shfl_xor(s, 2);
            s += __shfl_xor(s, 4); s += __shfl_xor(s, 8);
            sA[(row + g) * 128 + h * 16 + l15] = e / s;
        }
    }
    __syncthreads();

    // ---- offsets -> packed bilinear setup
    float rx[4], ry[4];
#pragma unroll
    for (int g = 0; g < 4; ++g) {
        rx[g] = refp[(long)(rbase + g) * 2];
        ry[g] = refp[(long)(rbase + g) * 2 + 1];
    }
#pragma unroll
    for (int j = 0; j < 16; ++j) {  // offset cols n = h*32 + l*8 + p*2 + xy
        int n = 16 * j + l15;
        int h = n >> 5, l = (n >> 3) & 3, p = (n >> 1) & 3, xy = n & 1;
        float bias = b_off[n];
        float scale = 2.0f * (float)(1 << l);
        const int Wl = 128 >> l;
        const float dim1 = (float)(Wl - 1);
        const int rowb = (l == 0) ? 0 : (l == 1) ? 16384 : (l == 2) ? 20480 : 21504;
#pragma unroll
        for (int g = 0; g < 4; ++g) {
            int r = rbase + g;
            float ref = xy ? ry[g] : rx[g];
            float px = ref * dim1 + tanhf(acc[j][g] + bias) * scale;
            float qy = __shfl_xor(px, 1);   // pair lanes: even has x, gets y
            if (!xy) {
                float x = px, y = qy;
                float fx = floorf(x), fy = floorf(y);
                int x0 = (int)fx, y0 = (int)fy;
                float wx = x - fx, wy = y - fy;
                bool vx0 = (x0 >= 0) && (x0 < Wl);
                bool vx1 = (x0 >= -1) && (x0 < Wl - 1);
                bool vy0 = (y0 >= 0) && (y0 < Wl);
                bool vy1 = (y0 >= -1) && (y0 < Wl - 1);
                uint2 pk;
                if ((vx0 | vx1) & (vy0 | vy1)) {
                    float a = sA[(row + g) * 128 + h * 16 + l * 4 + p];
                    float X0 = vx0 ? a * (1.f - wx) : 0.f;
                    float X1 = vx1 ? a * wx : 0.f;
                    int i00 = rowb + y0 * Wl + x0;          // signed, fits i16
                    int wy14 = (int)(wy * 16384.f);          // [0,16383]
                    unsigned int ypack = (unsigned int)wy14
                                       | (vy0 ? 0x4000u : 0u) | (vy1 ? 0x8000u : 0u);
                    pk.x = ((unsigned int)i00 & 0xffffu) | ((unsigned int)f2bf(X0) << 16);
                    pk.y = (unsigned int)f2bf(X1) | (ypack << 16);
                } else {
                    pk.x = 0u; pk.y = 0u;   // i00=0, all weights zero
                }
                sinfo[((long)r * 8 + h) * 16 + l * 4 + p] = pk;
            }
        }
    }
}

// ---------------- K2: vproj MFMA. Block tile 128o x 64s; D[o][s] = Wv[o][c]*feat[c][s]+bv
__global__ __launch_bounds__(256) void vproj_mfma(
    const float* __restrict__ feat0, const float* __restrict__ feat1,
    const float* __restrict__ feat2, const float* __restrict__ feat3,
    const unsigned short* __restrict__ wv,
    const float* __restrict__ bv0, const float* __restrict__ bv1,
    const float* __restrict__ bv2, const float* __restrict__ bv3,
    unsigned short* __restrict__ vbuf)
{
    __shared__ unsigned short aW[128 * LPAD];
    __shared__ unsigned short bF[64 * LPAD];
    const int blk = blockIdx.x;
    const int b = blk / 680;
    const int r = blk % 680;
    const float* feat; const unsigned short* wvl; const float* bvl; int S; long loff; int til;
    if (r < 512)      { til = r;       feat = feat0; wvl = wv;          bvl = bv0; S = 16384; loff = 0; }
    else if (r < 640) { til = r - 512; feat = feat1; wvl = wv + 65536;  bvl = bv1; S = 4096;  loff = 4194304; }
    else if (r < 672) { til = r - 640; feat = feat2; wvl = wv + 131072; bvl = bv2; S = 1024;  loff = 5242880; }
    else              { til = r - 672; feat = feat3; wvl = wv + 196608; bvl = bv3; S = 256;   loff = 5505024; }
    const int s0 = (til >> 1) * 64;
    const int o0 = (til & 1) * 128;
    const long fb = (long)b * 256 * S;
    const int t = threadIdx.x;
    const int w = t >> 6, lane = t & 63, quad = lane >> 4, l15 = lane & 15;

    floatx4 acc[2][4];
#pragma unroll
    for (int i = 0; i < 2; ++i)
#pragma unroll
        for (int j = 0; j < 4; ++j) acc[i][j] = (floatx4){0.f, 0.f, 0.f, 0.f};

    for (int k0 = 0; k0 < 256; k0 += 32) {
        __syncthreads();
        for (int i = 0; i < 2; ++i) {  // A: Wv 128 rows x 32k = 512 uint4
            int idx = i * 256 + t; int o = idx >> 2, kq = idx & 3;
            uint4 v = *(const uint4*)&wvl[(long)(o0 + o) * 256 + k0 + 8 * kq];
            *(uint4*)&aW[o * LPAD + 8 * kq] = v;
        }
        for (int i = 0; i < 8; ++i) {  // B: feat[k][s] -> LDS [s][c] (transpose)
            int idx = i * 256 + t; int s = idx & 63, c = idx >> 6;
            float v = feat[fb + (long)(k0 + c) * S + s0 + s];
            bF[s * LPAD + c] = f2bf(v);
        }
        __syncthreads();
        short8_t am0 = *(const short8_t*)&aW[(32 * w + l15) * LPAD + 8 * quad];
        short8_t am1 = *(const short8_t*)&aW[(32 * w + 16 + l15) * LPAD + 8 * quad];
#pragma unroll
        for (int j = 0; j < 4; ++j) {
            short8_t b8 = *(const short8_t*)&bF[(16 * j + l15) * LPAD + 8 * quad];
            acc[0][j] = MFMA16(am0, b8, acc[0][j]);
            acc[1][j] = MFMA16(am1, b8, acc[1][j]);
        }
    }

    unsigned short* vb = vbuf + (long)b * 5570560 + loff;
#pragma unroll
    for (int i = 0; i < 2; ++i) {
        int obase = o0 + 32 * w + 16 * i + 4 * quad;
        float4 bias = *(const float4*)&bvl[obase];
#pragma unroll
        for (int j = 0; j < 4; ++j) {
            int s = s0 + 16 * j + l15;
            short4_t pk;
            pk[0] = (short)f2bf(acc[i][j][0] + bias.x);
            pk[1] = (short)f2bf(acc[i][j][1] + bias.y);
            pk[2] = (short)f2bf(acc[i][j][2] + bias.z);
            pk[3] = (short)f2bf(acc[i][j][3] + bias.w);
            *(short4_t*)&vb[(long)s * 256 + obase] = pk;
        }
    }
}

// ---------------- K3: bilinear sampling, precomputed separable weights.
// 4 rows/block; lane owns 4 d-channels -> uint2 gathers (8B, 64B-contig per h-group).
// Stray (zero-weight) reads are bounded to the zeroed guard zones or finite vbuf data.
__global__ __launch_bounds__(256) void sample_kernel(
    const uint2* __restrict__ sinfo,
    const unsigned short* __restrict__ vbuf,
    unsigned short* __restrict__ preb)
{
    const int t = threadIdx.x;
    const int rsub = t >> 6;        // 4 rows per block
    const int h = (t >> 3) & 7;
    const int dq = t & 7;           // d = 4*dq .. 4*dq+3
    const int r = blockIdx.x * 4 + rsub;
    const int b = r >> 12;

    const uint2* info = sinfo + ((long)r * 8 + h) * 16;
    const unsigned short* V = vbuf + (long)b * 5570560 + h * 32 + 4 * dq;

    float o0 = 0.f, o1 = 0.f, o2 = 0.f, o3 = 0.f;
#pragma unroll
    for (int k = 0; k < 16; ++k) {
        const int l = k >> 2;
        const int Wl = 128 >> l;
        uint2 inf = info[k];
        int i00 = (int)(short)(inf.x & 0xffffu);     // sign-extend
        float X0 = __uint_as_float(inf.x & 0xffff0000u);
        float X1 = __uint_as_float(inf.y << 16);
        unsigned int yp = inf.y >> 16;
        float wy = (float)(yp & 0x3fffu) * (1.f / 16384.f);
        float Y1 = (yp & 0x8000u) ? wy : 0.f;
        float Y0 = (yp & 0x4000u) ? (1.f - wy) : 0.f;
        const unsigned short* b00 = V + (long)i00 * 256;
        const unsigned short* b10 = b00 + Wl * 256;
        uint2 g00 = *(const uint2*)(b00);
        uint2 g01 = *(const uint2*)(b00 + 256);
        uint2 g10 = *(const uint2*)(b10);
        uint2 g11 = *(const uint2*)(b10 + 256);
        float aw00 = X0 * Y0, aw01 = X1 * Y0, aw10 = X0 * Y1, aw11 = X1 * Y1;
        o0 += __uint_as_float(g00.x << 16) * aw00 + __uint_as_float(g01.x << 16) * aw01
            + __uint_as_float(g10.x << 16) * aw10 + __uint_as_float(g11.x << 16) * aw11;
        o1 += __uint_as_float(g00.x & 0xffff0000u) * aw00 + __uint_as_float(g01.x & 0xffff0000u) * aw01
            + __uint_as_float(g10.x & 0xffff0000u) * aw10 + __uint_as_float(g11.x & 0xffff0000u) * aw11;
        o2 += __uint_as_float(g00.y << 16) * aw00 + __uint_as_float(g01.y << 16) * aw01
            + __uint_as_float(g10.y << 16) * aw10 + __uint_as_float(g11.y << 16) * aw11;
        o3 += __uint_as_float(g00.y & 0xffff0000u) * aw00 + __uint_as_float(g01.y & 0xffff0000u) * aw01
            + __uint_as_float(g10.y & 0xffff0000u) * aw11 * 0.f
            + __uint_as_float(g10.y & 0xffff0000u) * aw10 + __uint_as_float(g11.y & 0xffff0000u) * aw11;
    }
    short4_t pk;
    pk[0] = (short)f2bf(o0); pk[1] = (short)f2bf(o1);
    pk[2] = (short)f2bf(o2); pk[3] = (short)f2bf(o3);
    *(short4_t*)&preb[(long)r * 256 + h * 32 + 4 * dq] = pk;
}

// ---------------- K4: outproj MFMA. D[j][r]; coalesced float4 stores.
__global__ __launch_bounds__(256) void outproj_mfma(
    const unsigned short* __restrict__ preb,
    const unsigned short* __restrict__ wo,
    const float* __restrict__ b_out,
    float* __restrict__ out)
{
    __shared__ unsigned short aJ[256 * LPAD];
    __shared__ unsigned short bR[64 * LPAD];
    const int t = threadIdx.x;
    const int r0 = blockIdx.x * 64;
    const int w = t >> 6, lane = t & 63, quad = lane >> 4, l15 = lane & 15;

    floatx4 acc[4][4];
#pragma unroll
    for (int i = 0; i < 4; ++i)
#pragma unroll
        for (int j = 0; j < 4; ++j) acc[i][j] = (floatx4){0.f, 0.f, 0.f, 0.f};

    for (int k0 = 0; k0 < 256; k0 += 32) {
        __syncthreads();
        for (int i = 0; i < 4; ++i) {  // A: woT 256 rows x 32k = 1024 uint4
            int idx = i * 256 + t; int j = idx >> 2, kq = idx & 3;
            uint4 v = *(const uint4*)&wo[(long)j * 256 + k0 + 8 * kq];
            *(uint4*)&aJ[j * LPAD + 8 * kq] = v;
        }
        {   // B: preb 64 rows x 32k = 256 uint4
            int rr = t >> 2, kq = t & 3;
            uint4 v = *(const uint4*)&preb[(long)(r0 + rr) * 256 + k0 + 8 * kq];
            *(uint4*)&bR[rr * LPAD + 8 * kq] = v;
        }
        __syncthreads();
        short8_t am[4];
#pragma unroll
        for (int mi = 0; mi < 4; ++mi)
            am[mi] = *(const short8_t*)&aJ[(64 * w + 16 * mi + l15) * LPAD + 8 * quad];
#pragma unroll
        for (int nj = 0; nj < 4; ++nj) {
            short8_t b8 = *(const short8_t*)&bR[(16 * nj + l15) * LPAD + 8 * quad];
#pragma unroll
            for (int mi = 0; mi < 4; ++mi)
                acc[mi][nj] = MFMA16(am[mi], b8, acc[mi][nj]);
        }
    }

#pragma unroll
    for (int mi = 0; mi < 4; ++mi) {
        int j0 = 64 * w + 16 * mi + 4 * quad;
        float4 bias = *(const float4*)&b_out[j0];
#pragma unroll
        for (int nj = 0; nj < 4; ++nj) {
            int r = r0 + 16 * nj + l15;
            float4 res;
            res.x = acc[mi][nj][0] + bias.x;
            res.y = acc[mi][nj][1] + bias.y;
            res.z = acc[mi][nj][2] + bias.z;
            res.w = acc[mi][nj][3] + bias.w;
            *(float4*)&out[(long)r * 256 + j0] = res;
        }
    }
}

extern "C" void kernel_launch(void* const* d_in, const int* in_sizes, int n_in,
                              void* d_out, int out_size, void* d_ws, size_t ws_size,
                              hipStream_t stream) {
    const float* query  = (const float*)d_in[0];
    const float* refp   = (const float*)d_in[1];
    const float* feat0  = (const float*)d_in[2];
    const float* feat1  = (const float*)d_in[3];
    const float* feat2  = (const float*)d_in[4];
    const float* feat3  = (const float*)d_in[5];
    const float* W_off  = (const float*)d_in[6];
    const float* b_off  = (const float*)d_in[7];
    const float* W_attn = (const float*)d_in[8];
    const float* b_attn = (const float*)d_in[9];
    const float* Wv0 = (const float*)d_in[10]; const float* bv0 = (const float*)d_in[11];
    const float* Wv1 = (const float*)d_in[12]; const float* bv1 = (const float*)d_in[13];
    const float* Wv2 = (const float*)d_in[14]; const float* bv2 = (const float*)d_in[15];
    const float* Wv3 = (const float*)d_in[16]; const float* bv3 = (const float*)d_in[17];
    const float* W_out = (const float*)d_in[18]; const float* b_out = (const float*)d_in[19];
    float* out = (float*)d_out;

    char* ws = (char*)d_ws;
    uint2*          sinfo = (uint2*)(ws + 0);
    uint4*          guard_lo = (uint4*)(ws + 33554432);
    unsigned short* vbuf = (unsigned short*)(ws + 33685504);
    uint4*          guard_hi = (uint4*)(ws + 122814464);
    unsigned short* preb = (unsigned short*)(ws + 122945536);
    unsigned short* wq   = (unsigned short*)(ws + 139722752);
    unsigned short* wv   = (unsigned short*)(ws + 139919360);
    unsigned short* wo   = (unsigned short*)(ws + 140443648);

    prep_kernel<<<64, 256, 0, stream>>>(W_off, W_attn, Wv0, Wv1, Wv2, Wv3, W_out,
                                        wq, wv, wo, guard_lo, guard_hi);
    qproj_mfma<<<512, 256, 0, stream>>>(query, refp, wq, b_off, b_attn, sinfo);
    vproj_mfma<<<5440, 256, 0, stream>>>(feat0, feat1, feat2, feat3, wv,
                                         bv0, bv1, bv2, bv3, vbuf);
    sample_kernel<<<8192, 256, 0, stream>>>(sinfo, vbuf, preb);
    outproj_mfma<<<512, 256, 0, stream>>>(preb, wo, b_out, out);
}

// Round 4
// 497.235 us; speedup vs baseline: 1.2770x; 1.0846x over previous
//
#include <hip/hip_runtime.h>
#include <math.h>

// B=8, Q=4096, C=256, H=8, D=32, L=4, P=4; levels 128/64/32/16 squared.
// R9: split qproj (was 140us, 77% stall: shfl-chain softmax + divergent epilogue at
// 23% occupancy) into qproj_gemm (pure MFMA -> f32 logits, coalesced) + setup_kernel
// (1 thread per (r,h): reg softmax, 32 ILP tanh, 128B coalesced sinfo stores).
// gout f32[32768][384] (50MB) overlaps vbuf region (dead until vproj; guards safe).
// ws layout (bytes):
//  sinfo uint2 @0 (33,554,432)
//  guard_lo @33,554,432 (131,072)
//  vbuf bf16 @33,685,504 (89,128,960) -> ends 122,814,464   [gout f32 @33,685,504
//     (50,331,648) lives here between qproj_gemm and setup_kernel]
//  guard_hi @122,814,464 (131,072)
//  preb bf16 @122,945,536 (16,777,216) -> ends 139,722,752
//  wqT bf16[384][256] @139,722,752 | wv bf16[4][256][256] @139,919,360
//  woT bf16[256][256] @140,443,648 -> end 140,574,720 (< proven 148,701,184)

typedef __attribute__((ext_vector_type(8))) short short8_t;
typedef __attribute__((ext_vector_type(4))) short short4_t;
typedef __attribute__((ext_vector_type(4))) float floatx4;

__device__ __forceinline__ float bf2f(unsigned short u) {
    return __uint_as_float(((unsigned int)u) << 16);
}
__device__ __forceinline__ unsigned short f2bf(float f) {
    unsigned int x = __float_as_uint(f);
    unsigned int r = x + 0x7fffu + ((x >> 16) & 1u);
    return (unsigned short)(r >> 16);
}

#define MFMA16(a, b, c) __builtin_amdgcn_mfma_f32_16x16x32_bf16((a), (b), (c), 0, 0, 0)
#define LPAD 40  // LDS row stride in shorts: 80 B = 16B-aligned frags, ~2-way banks (free)

// ---------------- K0: weight prep: cast + transpose to bf16; blocks 56..63 zero guards
__global__ __launch_bounds__(256) void prep_kernel(
    const float* __restrict__ W_off, const float* __restrict__ W_attn,
    const float* __restrict__ Wv0, const float* __restrict__ Wv1,
    const float* __restrict__ Wv2, const float* __restrict__ Wv3,
    const float* __restrict__ W_out,
    unsigned short* __restrict__ wq,
    unsigned short* __restrict__ wv,
    unsigned short* __restrict__ wo,
    uint4* __restrict__ guard_lo,
    uint4* __restrict__ guard_hi)
{
    const int t = threadIdx.x;
    const int blk = blockIdx.x;
    if (blk < 40) {
        __shared__ float tile[64][65];
        int n0, c0, ncols, nbase;
        const float* src;
        unsigned short* dst;
        if (blk < 24) {
            int tt = blk; n0 = (tt >> 2) * 64; c0 = (tt & 3) * 64;
            if (n0 < 256) { src = W_off; ncols = 256; nbase = n0; }
            else          { src = W_attn; ncols = 128; nbase = n0 - 256; }
            dst = wq;
        } else {
            int tt = blk - 24; n0 = (tt >> 2) * 64; c0 = (tt & 3) * 64;
            src = W_out; ncols = 256; nbase = n0; dst = wo;
        }
        for (int i = 0; i < 4; ++i) {
            int idx = i * 256 + t; int c = idx >> 4, n4 = idx & 15;
            float4 v = *(const float4*)&src[(long)(c0 + c) * ncols + nbase + 4 * n4];
            tile[4 * n4 + 0][c] = v.x; tile[4 * n4 + 1][c] = v.y;
            tile[4 * n4 + 2][c] = v.z; tile[4 * n4 + 3][c] = v.w;
        }
        __syncthreads();
        for (int i = 0; i < 4; ++i) {
            int idx = i * 256 + t; int n = idx >> 4, cg = idx & 15;
            short4_t pk;
            pk[0] = (short)f2bf(tile[n][4 * cg + 0]);
            pk[1] = (short)f2bf(tile[n][4 * cg + 1]);
            pk[2] = (short)f2bf(tile[n][4 * cg + 2]);
            pk[3] = (short)f2bf(tile[n][4 * cg + 3]);
            *(short4_t*)&dst[(long)(n0 + n) * 256 + c0 + 4 * cg] = pk;
        }
    } else if (blk < 56) {
        long g0 = (long)(blk - 40) * 16384;
        for (int i = 0; i < 16; ++i) {
            long e = g0 + (long)(i * 256 + t) * 4;
            int l = (int)(e >> 16); int off = (int)(e & 65535);
            const float* s = (l == 0) ? Wv0 : (l == 1) ? Wv1 : (l == 2) ? Wv2 : Wv3;
            float4 v = *(const float4*)&s[off];
            short4_t pk;
            pk[0] = (short)f2bf(v.x); pk[1] = (short)f2bf(v.y);
            pk[2] = (short)f2bf(v.z); pk[3] = (short)f2bf(v.w);
            *(short4_t*)&wv[e] = pk;
        }
    } else {
        // zero 128KB guard zones: 4 blocks each, 32768 B/block = 8 iters x 4096 B
        uint4 z = {0u, 0u, 0u, 0u};
        int sub = (blk - 56) & 3;
        uint4* g = (blk < 60) ? guard_lo : guard_hi;
        g += (long)sub * 2048 + t;   // uint4 units: 32768/16 = 2048 per block
        for (int i = 0; i < 8; ++i) g[i * 256] = z;
    }
}

// ---------------- K1a: qproj GEMM only. M=32768, N=384, K=256 -> gout f32[32768][384]
__global__ __launch_bounds__(256) void qproj_gemm(
    const float* __restrict__ query,
    const unsigned short* __restrict__ wq,
    float* __restrict__ gout)
{
    __shared__ unsigned short aT[64 * LPAD];
    __shared__ unsigned short bT[384 * LPAD];
    const int t = threadIdx.x;
    const int r0 = blockIdx.x * 64;
    const int w = t >> 6, lane = t & 63, quad = lane >> 4, l15 = lane & 15;

    floatx4 acc[24];
#pragma unroll
    for (int i = 0; i < 24; ++i) acc[i] = (floatx4){0.f, 0.f, 0.f, 0.f};

    for (int k0 = 0; k0 < 256; k0 += 32) {
        __syncthreads();
        for (int i = 0; i < 2; ++i) {  // A: query 64x32 fp32 -> bf16 (512 float4)
            int idx = i * 256 + t; int row = idx >> 3, kq = idx & 7;
            float4 v = *(const float4*)&query[(long)(r0 + row) * 256 + k0 + 4 * kq];
            short4_t pk;
            pk[0] = (short)f2bf(v.x); pk[1] = (short)f2bf(v.y);
            pk[2] = (short)f2bf(v.z); pk[3] = (short)f2bf(v.w);
            *(short4_t*)&aT[row * LPAD + 4 * kq] = pk;
        }
        for (int i = 0; i < 6; ++i) {  // B: wqT 384x32 bf16 (1536 uint4)
            int idx = i * 256 + t; int n = idx >> 2, kq = idx & 3;
            uint4 v = *(const uint4*)&wq[(long)n * 256 + k0 + 8 * kq];
            *(uint4*)&bT[n * LPAD + 8 * kq] = v;
        }
        __syncthreads();
        short8_t a8 = *(const short8_t*)&aT[(16 * w + l15) * LPAD + 8 * quad];
#pragma unroll
        for (int j = 0; j < 24; ++j) {
            short8_t b8 = *(const short8_t*)&bT[(16 * j + l15) * LPAD + 8 * quad];
            acc[j] = MFMA16(a8, b8, acc[j]);
        }
    }

    const int rbase = r0 + 16 * w + 4 * quad;
#pragma unroll
    for (int j = 0; j < 24; ++j) {
#pragma unroll
        for (int g = 0; g < 4; ++g)
            gout[(long)(rbase + g) * 384 + 16 * j + l15] = acc[j][g];
    }
}

// ---------------- K1b: setup. 1 thread per (r,h): reg softmax + tanh + pack sinfo.
// sinfo encoding: word0 = u16(i00 signed) | f2bf(X0)<<16
//                 word1 = f2bf(X1) | (wy14 | vy0<<14 | vy1<<15)<<16
// X0=a*(1-wx)*vx0, X1=a*wx*vx1, i00 = rowb + y0*Wl + x0 (unclamped). Fully-invalid
// points emit {0,0} so K3 reads stay within the guarded zones.
__global__ __launch_bounds__(256) void setup_kernel(
    const float* __restrict__ gout, const float* __restrict__ refp,
    const float* __restrict__ b_off, const float* __restrict__ b_attn,
    uint2* __restrict__ sinfo)
{
    const int t = threadIdx.x;
    const int h = t & 7;
    const int r = blockIdx.x * 32 + (t >> 3);
    const float* gl = gout + (long)r * 384;

    // softmax over the 16 attn logits (in registers, no cross-lane ops)
    float a[16];
    float m = -1e30f;
#pragma unroll
    for (int k = 0; k < 16; ++k) {
        a[k] = gl[256 + h * 16 + k] + b_attn[h * 16 + k];
        m = fmaxf(m, a[k]);
    }
    float s = 0.f;
#pragma unroll
    for (int k = 0; k < 16; ++k) { a[k] = __expf(a[k] - m); s += a[k]; }
    const float inv = 1.f / s;

    float off[32];
#pragma unroll
    for (int k = 0; k < 32; ++k) off[k] = gl[h * 32 + k] + b_off[h * 32 + k];
    const float rx = refp[(long)r * 2], ry = refp[(long)r * 2 + 1];

    uint2 pk[16];
#pragma unroll
    for (int k = 0; k < 16; ++k) {
        const int l = k >> 2;
        const int Wl = 128 >> l;
        const float dim1 = (float)(Wl - 1);
        const float scale = 2.0f * (float)(1 << l);
        const int rowb = (l == 0) ? 0 : (l == 1) ? 16384 : (l == 2) ? 20480 : 21504;
        float x = rx * dim1 + tanhf(off[2 * k]) * scale;
        float y = ry * dim1 + tanhf(off[2 * k + 1]) * scale;
        float fx = floorf(x), fy = floorf(y);
        int x0 = (int)fx, y0 = (int)fy;
        float wx = x - fx, wy = y - fy;
        bool vx0 = (x0 >= 0) && (x0 < Wl);
        bool vx1 = (x0 >= -1) && (x0 < Wl - 1);
        bool vy0 = (y0 >= 0) && (y0 < Wl);
        bool vy1 = (y0 >= -1) && (y0 < Wl - 1);
        if ((vx0 | vx1) & (vy0 | vy1)) {
            float av = a[k] * inv;
            float X0 = vx0 ? av * (1.f - wx) : 0.f;
            float X1 = vx1 ? av * wx : 0.f;
            int i00 = rowb + y0 * Wl + x0;           // signed, fits i16
            int wy14 = (int)(wy * 16384.f);          // [0,16383]
            unsigned int ypack = (unsigned int)wy14
                               | (vy0 ? 0x4000u : 0u) | (vy1 ? 0x8000u : 0u);
            pk[k].x = ((unsigned int)i00 & 0xffffu) | ((unsigned int)f2bf(X0) << 16);
            pk[k].y = (unsigned int)f2bf(X1) | (ypack << 16);
        } else {
            pk[k].x = 0u; pk[k].y = 0u;
        }
    }
    uint4* dst = (uint4*)(sinfo + ((long)r * 8 + h) * 16);
    const uint4* src = (const uint4*)pk;
#pragma unroll
    for (int i = 0; i < 8; ++i) dst[i] = src[i];
}

// ---------------- K2: vproj MFMA. Block tile 128o x 64s; D[o][s] = Wv[o][c]*feat[c][s]+bv
__global__ __launch_bounds__(256) void vproj_mfma(
    const float* __restrict__ feat0, const float* __restrict__ feat1,
    const float* __restrict__ feat2, const float* __restrict__ feat3,
    const unsigned short* __restrict__ wv,
    const float* __restrict__ bv0, const float* __restrict__ bv1,
    const float* __restrict__ bv2, const float* __restrict__ bv3,
    unsigned short* __restrict__ vbuf)
{
    __shared__ unsigned short aW[128 * LPAD];
    __shared__ unsigned short bF[64 * LPAD];
    const int blk = blockIdx.x;
    const int b = blk / 680;
    const int r = blk % 680;
    const float* feat; const unsigned short* wvl; const float* bvl; int S; long loff; int til;
    if (r < 512)      { til = r;       feat = feat0; wvl = wv;          bvl = bv0; S = 16384; loff = 0; }
    else if (r < 640) { til = r - 512; feat = feat1; wvl = wv + 65536;  bvl = bv1; S = 4096;  loff = 4194304; }
    else if (r < 672) { til = r - 640; feat = feat2; wvl = wv + 131072; bvl = bv2; S = 1024;  loff = 5242880; }
    else              { til = r - 672; feat = feat3; wvl = wv + 196608; bvl = bv3; S = 256;   loff = 5505024; }
    const int s0 = (til >> 1) * 64;
    const int o0 = (til & 1) * 128;
    const long fb = (long)b * 256 * S;
    const int t = threadIdx.x;
    const int w = t >> 6, lane = t & 63, quad = lane >> 4, l15 = lane & 15;

    floatx4 acc[2][4];
#pragma unroll
    for (int i = 0; i < 2; ++i)
#pragma unroll
        for (int j = 0; j < 4; ++j) acc[i][j] = (floatx4){0.f, 0.f, 0.f, 0.f};

    for (int k0 = 0; k0 < 256; k0 += 32) {
        __syncthreads();
        for (int i = 0; i < 2; ++i) {  // A: Wv 128 rows x 32k = 512 uint4
            int idx = i * 256 + t; int o = idx >> 2, kq = idx & 3;
            uint4 v = *(const uint4*)&wvl[(long)(o0 + o) * 256 + k0 + 8 * kq];
            *(uint4*)&aW[o * LPAD + 8 * kq] = v;
        }
        for (int i = 0; i < 8; ++i) {  // B: feat[k][s] -> LDS [s][c] (transpose)
            int idx = i * 256 + t; int s = idx & 63, c = idx >> 6;
            float v = feat[fb + (long)(k0 + c) * S + s0 + s];
            bF[s * LPAD + c] = f2bf(v);
        }
        __syncthreads();
        short8_t am0 = *(const short8_t*)&aW[(32 * w + l15) * LPAD + 8 * quad];
        short8_t am1 = *(const short8_t*)&aW[(32 * w + 16 + l15) * LPAD + 8 * quad];
#pragma unroll
        for (int j = 0; j < 4; ++j) {
            short8_t b8 = *(const short8_t*)&bF[(16 * j + l15) * LPAD + 8 * quad];
            acc[0][j] = MFMA16(am0, b8, acc[0][j]);
            acc[1][j] = MFMA16(am1, b8, acc[1][j]);
        }
    }

    unsigned short* vb = vbuf + (long)b * 5570560 + loff;
#pragma unroll
    for (int i = 0; i < 2; ++i) {
        int obase = o0 + 32 * w + 16 * i + 4 * quad;
        float4 bias = *(const float4*)&bvl[obase];
#pragma unroll
        for (int j = 0; j < 4; ++j) {
            int s = s0 + 16 * j + l15;
            short4_t pk;
            pk[0] = (short)f2bf(acc[i][j][0] + bias.x);
            pk[1] = (short)f2bf(acc[i][j][1] + bias.y);
            pk[2] = (short)f2bf(acc[i][j][2] + bias.z);
            pk[3] = (short)f2bf(acc[i][j][3] + bias.w);
            *(short4_t*)&vb[(long)s * 256 + obase] = pk;
        }
    }
}

// ---------------- K3: bilinear sampling, precomputed separable weights.
// 4 rows/block; lane owns 4 d-channels -> uint2 gathers (8B, 64B-contig per h-group).
// Stray (zero-weight) reads are bounded to the zeroed guard zones or finite vbuf data.
__global__ __launch_bounds__(256) void sample_kernel(
    const uint2* __restrict__ sinfo,
    const unsigned short* __restrict__ vbuf,
    unsigned short* __restrict__ preb)
{
    const int t = threadIdx.x;
    const int rsub = t >> 6;        // 4 rows per block
    const int h = (t >> 3) & 7;
    const int dq = t & 7;           // d = 4*dq .. 4*dq+3
    const int r = blockIdx.x * 4 + rsub;
    const int b = r >> 12;

    const uint2* info = sinfo + ((long)r * 8 + h) * 16;
    const unsigned short* V = vbuf + (long)b * 5570560 + h * 32 + 4 * dq;

    float o0 = 0.f, o1 = 0.f, o2 = 0.f, o3 = 0.f;
#pragma unroll
    for (int k = 0; k < 16; ++k) {
        const int l = k >> 2;
        const int Wl = 128 >> l;
        uint2 inf = info[k];
        int i00 = (int)(short)(inf.x & 0xffffu);     // sign-extend
        float X0 = __uint_as_float(inf.x & 0xffff0000u);
        float X1 = __uint_as_float(inf.y << 16);
        unsigned int yp = inf.y >> 16;
        float wy = (float)(yp & 0x3fffu) * (1.f / 16384.f);
        float Y1 = (yp & 0x8000u) ? wy : 0.f;
        float Y0 = (yp & 0x4000u) ? (1.f - wy) : 0.f;
        const unsigned short* b00 = V + (long)i00 * 256;
        const unsigned short* b10 = b00 + Wl * 256;
        uint2 g00 = *(const uint2*)(b00);
        uint2 g01 = *(const uint2*)(b00 + 256);
        uint2 g10 = *(const uint2*)(b10);
        uint2 g11 = *(const uint2*)(b10 + 256);
        float aw00 = X0 * Y0, aw01 = X1 * Y0, aw10 = X0 * Y1, aw11 = X1 * Y1;
        o0 += __uint_as_float(g00.x << 16) * aw00 + __uint_as_float(g01.x << 16) * aw01
            + __uint_as_float(g10.x << 16) * aw10 + __uint_as_float(g11.x << 16) * aw11;
        o1 += __uint_as_float(g00.x & 0xffff0000u) * aw00 + __uint_as_float(g01.x & 0xffff0000u) * aw01
            + __uint_as_float(g10.x & 0xffff0000u) * aw10 + __uint_as_float(g11.x & 0xffff0000u) * aw11;
        o2 += __uint_as_float(g00.y << 16) * aw00 + __uint_as_float(g01.y << 16) * aw01
            + __uint_as_float(g10.y << 16) * aw10 + __uint_as_float(g11.y << 16) * aw11;
        o3 += __uint_as_float(g00.y & 0xffff0000u) * aw00 + __uint_as_float(g01.y & 0xffff0000u) * aw01
            + __uint_as_float(g10.y & 0xffff0000u) * aw10 + __uint_as_float(g11.y & 0xffff0000u) * aw11;
    }
    short4_t pk;
    pk[0] = (short)f2bf(o0); pk[1] = (short)f2bf(o1);
    pk[2] = (short)f2bf(o2); pk[3] = (short)f2bf(o3);
    *(short4_t*)&preb[(long)r * 256 + h * 32 + 4 * dq] = pk;
}

// ---------------- K4: outproj MFMA. D[j][r]; coalesced float4 stores.
__global__ __launch_bounds__(256) void outproj_mfma(
    const unsigned short* __restrict__ preb,
    const unsigned short* __restrict__ wo,
    const float* __restrict__ b_out,
    float* __restrict__ out)
{
    __shared__ unsigned short aJ[256 * LPAD];
    __shared__ unsigned short bR[64 * LPAD];
    const int t = threadIdx.x;
    const int r0 = blockIdx.x * 64;
    const int w = t >> 6, lane = t & 63, quad = lane >> 4, l15 = lane & 15;

    floatx4 acc[4][4];
#pragma unroll
    for (int i = 0; i < 4; ++i)
#pragma unroll
        for (int j = 0; j < 4; ++j) acc[i][j] = (floatx4){0.f, 0.f, 0.f, 0.f};

    for (int k0 = 0; k0 < 256; k0 += 32) {
        __syncthreads();
        for (int i = 0; i < 4; ++i) {  // A: woT 256 rows x 32k = 1024 uint4
            int idx = i * 256 + t; int j = idx >> 2, kq = idx & 3;
            uint4 v = *(const uint4*)&wo[(long)j * 256 + k0 + 8 * kq];
            *(uint4*)&aJ[j * LPAD + 8 * kq] = v;
        }
        {   // B: preb 64 rows x 32k = 256 uint4
            int rr = t >> 2, kq = t & 3;
            uint4 v = *(const uint4*)&preb[(long)(r0 + rr) * 256 + k0 + 8 * kq];
            *(uint4*)&bR[rr * LPAD + 8 * kq] = v;
        }
        __syncthreads();
        short8_t am[4];
#pragma unroll
        for (int mi = 0; mi < 4; ++mi)
            am[mi] = *(const short8_t*)&aJ[(64 * w + 16 * mi + l15) * LPAD + 8 * quad];
#pragma unroll
        for (int nj = 0; nj < 4; ++nj) {
            short8_t b8 = *(const short8_t*)&bR[(16 * nj + l15) * LPAD + 8 * quad];
#pragma unroll
            for (int mi = 0; mi < 4; ++mi)
                acc[mi][nj] = MFMA16(am[mi], b8, acc[mi][nj]);
        }
    }

#pragma unroll
    for (int mi = 0; mi < 4; ++mi) {
        int j0 = 64 * w + 16 * mi + 4 * quad;
        float4 bias = *(const float4*)&b_out[j0];
#pragma unroll
        for (int nj = 0; nj < 4; ++nj) {
            int r = r0 + 16 * nj + l15;
            float4 res;
            res.x = acc[mi][nj][0] + bias.x;
            res.y = acc[mi][nj][1] + bias.y;
            res.z = acc[mi][nj][2] + bias.z;
            res.w = acc[mi][nj][3] + bias.w;
            *(float4*)&out[(long)r * 256 + j0] = res;
        }
    }
}

extern "C" void kernel_launch(void* const* d_in, const int* in_sizes, int n_in,
                              void* d_out, int out_size, void* d_ws, size_t ws_size,
                              hipStream_t stream) {
    const float* query  = (const float*)d_in[0];
    const float* refp   = (const float*)d_in[1];
    const float* feat0  = (const float*)d_in[2];
    const float* feat1  = (const float*)d_in[3];
    const float* feat2  = (const float*)d_in[4];
    const float* feat3  = (const float*)d_in[5];
    const float* W_off  = (const float*)d_in[6];
    const float* b_off  = (const float*)d_in[7];
    const float* W_attn = (const float*)d_in[8];
    const float* b_attn = (const float*)d_in[9];
    const float* Wv0 = (const float*)d_in[10]; const float* bv0 = (const float*)d_in[11];
    const float* Wv1 = (const float*)d_in[12]; const float* bv1 = (const float*)d_in[13];
    const float* Wv2 = (const float*)d_in[14]; const float* bv2 = (const float*)d_in[15];
    const float* Wv3 = (const float*)d_in[16]; const float* bv3 = (const float*)d_in[17];
    const float* W_out = (const float*)d_in[18]; const float* b_out = (const float*)d_in[19];
    float* out = (float*)d_out;

    char* ws = (char*)d_ws;
    uint2*          sinfo = (uint2*)(ws + 0);
    uint4*          guard_lo = (uint4*)(ws + 33554432);
    unsigned short* vbuf = (unsigned short*)(ws + 33685504);
    float*          gout = (float*)(ws + 33685504);   // overlaps vbuf (dead until vproj)
    uint4*          guard_hi = (uint4*)(ws + 122814464);
    unsigned short* preb = (unsigned short*)(ws + 122945536);
    unsigned short* wq   = (unsigned short*)(ws + 139722752);
    unsigned short* wv   = (unsigned short*)(ws + 139919360);
    unsigned short* wo   = (unsigned short*)(ws + 140443648);

    prep_kernel<<<64, 256, 0, stream>>>(W_off, W_attn, Wv0, Wv1, Wv2, Wv3, W_out,
                                        wq, wv, wo, guard_lo, guard_hi);
    qproj_gemm<<<512, 256, 0, stream>>>(query, wq, gout);
    setup_kernel<<<1024, 256, 0, stream>>>(gout, refp, b_off, b_attn, sinfo);
    vproj_mfma<<<5440, 256, 0, stream>>>(feat0, feat1, feat2, feat3, wv,
                                         bv0, bv1, bv2, bv3, vbuf);
    sample_kernel<<<8192, 256, 0, stream>>>(sinfo, vbuf, preb);
    outproj_mfma<<<512, 256, 0, stream>>>(preb, wo, b_out, out);
}

// Round 5
// 491.694 us; speedup vs baseline: 1.2914x; 1.0113x over previous
//
#include <hip/hip_runtime.h>
#include <math.h>

// B=8, Q=4096, C=256, H=8, D=32, L=4, P=4; levels 128/64/32/16 squared.
// R10: vproj rewrite. Old: 120us, 15.3M LDS conflicts (scalar 2B transposed stores,
// wave-uniform c -> 8-way), 8 MFMA per 2-barrier k-step, feat fetched 2x/block-pair.
// New: 256o x 64s tile (2720 blocks), feat staged f32 [c][s] via float4+b128
// (conflict-free), wave w owns s-range [16w,16w+16) and builds B-frags with 8x
// ds_read_b32 down a column (~1.25-way) + in-lane cvt; 16 MFMA per wave per k-step.
// ws layout (bytes):
//  sinfo uint2 @0 (33,554,432)
//  guard_lo @33,554,432 (131,072)
//  vbuf bf16 @33,685,504 (89,128,960) -> ends 122,814,464   [gout f32 @33,685,504
//     (50,331,648) lives here between qproj_gemm and setup_kernel]
//  guard_hi @122,814,464 (131,072)
//  preb bf16 @122,945,536 (16,777,216) -> ends 139,722,752
//  wqT bf16[384][256] @139,722,752 | wv bf16[4][256][256] @139,919,360
//  woT bf16[256][256] @140,443,648 -> end 140,574,720 (< proven 148,701,184)

typedef __attribute__((ext_vector_type(8))) short short8_t;
typedef __attribute__((ext_vector_type(4))) short short4_t;
typedef __attribute__((ext_vector_type(4))) float floatx4;

__device__ __forceinline__ float bf2f(unsigned short u) {
    return __uint_as_float(((unsigned int)u) << 16);
}
__device__ __forceinline__ unsigned short f2bf(float f) {
    unsigned int x = __float_as_uint(f);
    unsigned int r = x + 0x7fffu + ((x >> 16) & 1u);
    return (unsigned short)(r >> 16);
}

#define MFMA16(a, b, c) __builtin_amdgcn_mfma_f32_16x16x32_bf16((a), (b), (c), 0, 0, 0)
#define LPAD 40  // LDS row stride in shorts: 80 B = 16B-aligned frags, ~2-way banks (free)

// ---------------- K0: weight prep: cast + transpose to bf16; blocks 56..63 zero guards
__global__ __launch_bounds__(256) void prep_kernel(
    const float* __restrict__ W_off, const float* __restrict__ W_attn,
    const float* __restrict__ Wv0, const float* __restrict__ Wv1,
    const float* __restrict__ Wv2, const float* __restrict__ Wv3,
    const float* __restrict__ W_out,
    unsigned short* __restrict__ wq,
    unsigned short* __restrict__ wv,
    unsigned short* __restrict__ wo,
    uint4* __restrict__ guard_lo,
    uint4* __restrict__ guard_hi)
{
    const int t = threadIdx.x;
    const int blk = blockIdx.x;
    if (blk < 40) {
        __shared__ float tile[64][65];
        int n0, c0, ncols, nbase;
        const float* src;
        unsigned short* dst;
        if (blk < 24) {
            int tt = blk; n0 = (tt >> 2) * 64; c0 = (tt & 3) * 64;
            if (n0 < 256) { src = W_off; ncols = 256; nbase = n0; }
            else          { src = W_attn; ncols = 128; nbase = n0 - 256; }
            dst = wq;
        } else {
            int tt = blk - 24; n0 = (tt >> 2) * 64; c0 = (tt & 3) * 64;
            src = W_out; ncols = 256; nbase = n0; dst = wo;
        }
        for (int i = 0; i < 4; ++i) {
            int idx = i * 256 + t; int c = idx >> 4, n4 = idx & 15;
            float4 v = *(const float4*)&src[(long)(c0 + c) * ncols + nbase + 4 * n4];
            tile[4 * n4 + 0][c] = v.x; tile[4 * n4 + 1][c] = v.y;
            tile[4 * n4 + 2][c] = v.z; tile[4 * n4 + 3][c] = v.w;
        }
        __syncthreads();
        for (int i = 0; i < 4; ++i) {
            int idx = i * 256 + t; int n = idx >> 4, cg = idx & 15;
            short4_t pk;
            pk[0] = (short)f2bf(tile[n][4 * cg + 0]);
            pk[1] = (short)f2bf(tile[n][4 * cg + 1]);
            pk[2] = (short)f2bf(tile[n][4 * cg + 2]);
            pk[3] = (short)f2bf(tile[n][4 * cg + 3]);
            *(short4_t*)&dst[(long)(n0 + n) * 256 + c0 + 4 * cg] = pk;
        }
    } else if (blk < 56) {
        long g0 = (long)(blk - 40) * 16384;
        for (int i = 0; i < 16; ++i) {
            long e = g0 + (long)(i * 256 + t) * 4;
            int l = (int)(e >> 16); int off = (int)(e & 65535);
            const float* s = (l == 0) ? Wv0 : (l == 1) ? Wv1 : (l == 2) ? Wv2 : Wv3;
            float4 v = *(const float4*)&s[off];
            short4_t pk;
            pk[0] = (short)f2bf(v.x); pk[1] = (short)f2bf(v.y);
            pk[2] = (short)f2bf(v.z); pk[3] = (short)f2bf(v.w);
            *(short4_t*)&wv[e] = pk;
        }
    } else {
        // zero 128KB guard zones: 4 blocks each, 32768 B/block = 8 iters x 4096 B
        uint4 z = {0u, 0u, 0u, 0u};
        int sub = (blk - 56) & 3;
        uint4* g = (blk < 60) ? guard_lo : guard_hi;
        g += (long)sub * 2048 + t;   // uint4 units: 32768/16 = 2048 per block
        for (int i = 0; i < 8; ++i) g[i * 256] = z;
    }
}

// ---------------- K1a: qproj GEMM only. M=32768, N=384, K=256 -> gout f32[32768][384]
__global__ __launch_bounds__(256) void qproj_gemm(
    const float* __restrict__ query,
    const unsigned short* __restrict__ wq,
    float* __restrict__ gout)
{
    __shared__ unsigned short aT[64 * LPAD];
    __shared__ unsigned short bT[384 * LPAD];
    const int t = threadIdx.x;
    const int r0 = blockIdx.x * 64;
    const int w = t >> 6, lane = t & 63, quad = lane >> 4, l15 = lane & 15;

    floatx4 acc[24];
#pragma unroll
    for (int i = 0; i < 24; ++i) acc[i] = (floatx4){0.f, 0.f, 0.f, 0.f};

    for (int k0 = 0; k0 < 256; k0 += 32) {
        __syncthreads();
        for (int i = 0; i < 2; ++i) {  // A: query 64x32 fp32 -> bf16 (512 float4)
            int idx = i * 256 + t; int row = idx >> 3, kq = idx & 7;
            float4 v = *(const float4*)&query[(long)(r0 + row) * 256 + k0 + 4 * kq];
            short4_t pk;
            pk[0] = (short)f2bf(v.x); pk[1] = (short)f2bf(v.y);
            pk[2] = (short)f2bf(v.z); pk[3] = (short)f2bf(v.w);
            *(short4_t*)&aT[row * LPAD + 4 * kq] = pk;
        }
        for (int i = 0; i < 6; ++i) {  // B: wqT 384x32 bf16 (1536 uint4)
            int idx = i * 256 + t; int n = idx >> 2, kq = idx & 3;
            uint4 v = *(const uint4*)&wq[(long)n * 256 + k0 + 8 * kq];
            *(uint4*)&bT[n * LPAD + 8 * kq] = v;
        }
        __syncthreads();
        short8_t a8 = *(const short8_t*)&aT[(16 * w + l15) * LPAD + 8 * quad];
#pragma unroll
        for (int j = 0; j < 24; ++j) {
            short8_t b8 = *(const short8_t*)&bT[(16 * j + l15) * LPAD + 8 * quad];
            acc[j] = MFMA16(a8, b8, acc[j]);
        }
    }

    const int rbase = r0 + 16 * w + 4 * quad;
#pragma unroll
    for (int j = 0; j < 24; ++j) {
#pragma unroll
        for (int g = 0; g < 4; ++g)
            gout[(long)(rbase + g) * 384 + 16 * j + l15] = acc[j][g];
    }
}

// ---------------- K1b: setup. 1 thread per (r,h): reg softmax + tanh + pack sinfo.
// sinfo encoding: word0 = u16(i00 signed) | f2bf(X0)<<16
//                 word1 = f2bf(X1) | (wy14 | vy0<<14 | vy1<<15)<<16
// X0=a*(1-wx)*vx0, X1=a*wx*vx1, i00 = rowb + y0*Wl + x0 (unclamped). Fully-invalid
// points emit {0,0} so K3 reads stay within the guarded zones.
__global__ __launch_bounds__(256) void setup_kernel(
    const float* __restrict__ gout, const float* __restrict__ refp,
    const float* __restrict__ b_off, const float* __restrict__ b_attn,
    uint2* __restrict__ sinfo)
{
    const int t = threadIdx.x;
    const int h = t & 7;
    const int r = blockIdx.x * 32 + (t >> 3);
    const float* gl = gout + (long)r * 384;

    // softmax over the 16 attn logits (in registers, no cross-lane ops)
    float a[16];
    float m = -1e30f;
#pragma unroll
    for (int k = 0; k < 16; ++k) {
        a[k] = gl[256 + h * 16 + k] + b_attn[h * 16 + k];
        m = fmaxf(m, a[k]);
    }
    float s = 0.f;
#pragma unroll
    for (int k = 0; k < 16; ++k) { a[k] = __expf(a[k] - m); s += a[k]; }
    const float inv = 1.f / s;

    float off[32];
#pragma unroll
    for (int k = 0; k < 32; ++k) off[k] = gl[h * 32 + k] + b_off[h * 32 + k];
    const float rx = refp[(long)r * 2], ry = refp[(long)r * 2 + 1];

    uint2 pk[16];
#pragma unroll
    for (int k = 0; k < 16; ++k) {
        const int l = k >> 2;
        const int Wl = 128 >> l;
        const float dim1 = (float)(Wl - 1);
        const float scale = 2.0f * (float)(1 << l);
        const int rowb = (l == 0) ? 0 : (l == 1) ? 16384 : (l == 2) ? 20480 : 21504;
        float x = rx * dim1 + tanhf(off[2 * k]) * scale;
        float y = ry * dim1 + tanhf(off[2 * k + 1]) * scale;
        float fx = floorf(x), fy = floorf(y);
        int x0 = (int)fx, y0 = (int)fy;
        float wx = x - fx, wy = y - fy;
        bool vx0 = (x0 >= 0) && (x0 < Wl);
        bool vx1 = (x0 >= -1) && (x0 < Wl - 1);
        bool vy0 = (y0 >= 0) && (y0 < Wl);
        bool vy1 = (y0 >= -1) && (y0 < Wl - 1);
        if ((vx0 | vx1) & (vy0 | vy1)) {
            float av = a[k] * inv;
            float X0 = vx0 ? av * (1.f - wx) : 0.f;
            float X1 = vx1 ? av * wx : 0.f;
            int i00 = rowb + y0 * Wl + x0;           // signed, fits i16
            int wy14 = (int)(wy * 16384.f);          // [0,16383]
            unsigned int ypack = (unsigned int)wy14
                               | (vy0 ? 0x4000u : 0u) | (vy1 ? 0x8000u : 0u);
            pk[k].x = ((unsigned int)i00 & 0xffffu) | ((unsigned int)f2bf(X0) << 16);
            pk[k].y = (unsigned int)f2bf(X1) | (ypack << 16);
        } else {
            pk[k].x = 0u; pk[k].y = 0u;
        }
    }
    uint4* dst = (uint4*)(sinfo + ((long)r * 8 + h) * 16);
    const uint4* src = (const uint4*)pk;
#pragma unroll
    for (int i = 0; i < 8; ++i) dst[i] = src[i];
}

// ---------------- K2: vproj MFMA. Block tile 256o x 64s; wave w owns s-range
// [16w,16w+16). feat staged f32 [c][s] (conflict-free b128); B-frag = 8x ds_read_b32
// down a column + in-lane bf16 cvt; A (Wv) staged bf16 as before; 16 MFMA/wave/k-step.
__global__ __launch_bounds__(256) void vproj_mfma(
    const float* __restrict__ feat0, const float* __restrict__ feat1,
    const float* __restrict__ feat2, const float* __restrict__ feat3,
    const unsigned short* __restrict__ wv,
    const float* __restrict__ bv0, const float* __restrict__ bv1,
    const float* __restrict__ bv2, const float* __restrict__ bv3,
    unsigned short* __restrict__ vbuf)
{
    __shared__ unsigned short aW[256 * LPAD];   // 20480 B
    __shared__ float fT[32][65];                // 8320 B
    const int blk = blockIdx.x;
    const int b = blk / 340;
    const int r = blk % 340;
    const float* feat; const unsigned short* wvl; const float* bvl; int S; long loff; int til;
    if (r < 256)      { til = r;       feat = feat0; wvl = wv;          bvl = bv0; S = 16384; loff = 0; }
    else if (r < 320) { til = r - 256; feat = feat1; wvl = wv + 65536;  bvl = bv1; S = 4096;  loff = 4194304; }
    else if (r < 336) { til = r - 320; feat = feat2; wvl = wv + 131072; bvl = bv2; S = 1024;  loff = 5242880; }
    else              { til = r - 336; feat = feat3; wvl = wv + 196608; bvl = bv3; S = 256;   loff = 5505024; }
    const int s0 = til * 64;
    const long fb = (long)b * 256 * S;
    const int t = threadIdx.x;
    const int w = t >> 6, lane = t & 63, quad = lane >> 4, l15 = lane & 15;
    const int smy = 16 * w + l15;   // this lane's s within the 64-tile

    floatx4 acc[16];
#pragma unroll
    for (int i = 0; i < 16; ++i) acc[i] = (floatx4){0.f, 0.f, 0.f, 0.f};

    for (int k0 = 0; k0 < 256; k0 += 32) {
        __syncthreads();
        for (int i = 0; i < 4; ++i) {  // A: Wv 256 rows x 32k = 1024 uint4
            int idx = i * 256 + t; int o = idx >> 2, kq = idx & 3;
            uint4 v = *(const uint4*)&wvl[(long)o * 256 + k0 + 8 * kq];
            *(uint4*)&aW[o * LPAD + 8 * kq] = v;
        }
        for (int i = 0; i < 2; ++i) {  // B: feat 32c x 64s f32 = 512 float4
            int idx = i * 256 + t; int c = idx >> 4, s4 = idx & 15;
            float4 v = *(const float4*)&feat[fb + (long)(k0 + c) * S + s0 + 4 * s4];
            *(float4*)&fT[c][4 * s4] = v;
        }
        __syncthreads();
        // B-frag: lane (quad,l15) of wave w: B[n=l15][k=8q+i] = fT[8q+i][16w+l15]
        float bvv[8];
#pragma unroll
        for (int i = 0; i < 8; ++i) bvv[i] = fT[8 * quad + i][smy];
        short8_t b8;
#pragma unroll
        for (int i = 0; i < 8; ++i) b8[i] = (short)f2bf(bvv[i]);
#pragma unroll
        for (int mi = 0; mi < 16; ++mi) {
            short8_t a8 = *(const short8_t*)&aW[(16 * mi + l15) * LPAD + 8 * quad];
            acc[mi] = MFMA16(a8, b8, acc[mi]);
        }
    }

    unsigned short* vb = vbuf + (long)b * 5570560 + loff;
    const int s = s0 + smy;
#pragma unroll
    for (int mi = 0; mi < 16; ++mi) {
        int obase = 16 * mi + 4 * quad;
        float4 bias = *(const float4*)&bvl[obase];
        short4_t pk;
        pk[0] = (short)f2bf(acc[mi][0] + bias.x);
        pk[1] = (short)f2bf(acc[mi][1] + bias.y);
        pk[2] = (short)f2bf(acc[mi][2] + bias.z);
        pk[3] = (short)f2bf(acc[mi][3] + bias.w);
        *(short4_t*)&vb[(long)s * 256 + obase] = pk;
    }
}

// ---------------- K3: bilinear sampling, precomputed separable weights.
// 4 rows/block; lane owns 4 d-channels -> uint2 gathers (8B, 64B-contig per h-group).
// Stray (zero-weight) reads are bounded to the zeroed guard zones or finite vbuf data.
__global__ __launch_bounds__(256) void sample_kernel(
    const uint2* __restrict__ sinfo,
    const unsigned short* __restrict__ vbuf,
    unsigned short* __restrict__ preb)
{
    const int t = threadIdx.x;
    const int rsub = t >> 6;        // 4 rows per block
    const int h = (t >> 3) & 7;
    const int dq = t & 7;           // d = 4*dq .. 4*dq+3
    const int r = blockIdx.x * 4 + rsub;
    const int b = r >> 12;

    const uint2* info = sinfo + ((long)r * 8 + h) * 16;
    const unsigned short* V = vbuf + (long)b * 5570560 + h * 32 + 4 * dq;

    float o0 = 0.f, o1 = 0.f, o2 = 0.f, o3 = 0.f;
#pragma unroll
    for (int k = 0; k < 16; ++k) {
        const int l = k >> 2;
        const int Wl = 128 >> l;
        uint2 inf = info[k];
        int i00 = (int)(short)(inf.x & 0xffffu);     // sign-extend
        float X0 = __uint_as_float(inf.x & 0xffff0000u);
        float X1 = __uint_as_float(inf.y << 16);
        unsigned int yp = inf.y >> 16;
        float wy = (float)(yp & 0x3fffu) * (1.f / 16384.f);
        float Y1 = (yp & 0x8000u) ? wy : 0.f;
        float Y0 = (yp & 0x4000u) ? (1.f - wy) : 0.f;
        const unsigned short* b00 = V + (long)i00 * 256;
        const unsigned short* b10 = b00 + Wl * 256;
        uint2 g00 = *(const uint2*)(b00);
        uint2 g01 = *(const uint2*)(b00 + 256);
        uint2 g10 = *(const uint2*)(b10);
        uint2 g11 = *(const uint2*)(b10 + 256);
        float aw00 = X0 * Y0, aw01 = X1 * Y0, aw10 = X0 * Y1, aw11 = X1 * Y1;
        o0 += __uint_as_float(g00.x << 16) * aw00 + __uint_as_float(g01.x << 16) * aw01
            + __uint_as_float(g10.x << 16) * aw10 + __uint_as_float(g11.x << 16) * aw11;
        o1 += __uint_as_float(g00.x & 0xffff0000u) * aw00 + __uint_as_float(g01.x & 0xffff0000u) * aw01
            + __uint_as_float(g10.x & 0xffff0000u) * aw10 + __uint_as_float(g11.x & 0xffff0000u) * aw11;
        o2 += __uint_as_float(g00.y << 16) * aw00 + __uint_as_float(g01.y << 16) * aw01
            + __uint_as_float(g10.y << 16) * aw10 + __uint_as_float(g11.y << 16) * aw11;
        o3 += __uint_as_float(g00.y & 0xffff0000u) * aw00 + __uint_as_float(g01.y & 0xffff0000u) * aw01
            + __uint_as_float(g10.y & 0xffff0000u) * aw10 + __uint_as_float(g11.y & 0xffff0000u) * aw11;
    }
    short4_t pk;
    pk[0] = (short)f2bf(o0); pk[1] = (short)f2bf(o1);
    pk[2] = (short)f2bf(o2); pk[3] = (short)f2bf(o3);
    *(short4_t*)&preb[(long)r * 256 + h * 32 + 4 * dq] = pk;
}

// ---------------- K4: outproj MFMA. D[j][r]; coalesced float4 stores.
__global__ __launch_bounds__(256) void outproj_mfma(
    const unsigned short* __restrict__ preb,
    const unsigned short* __restrict__ wo,
    const float* __restrict__ b_out,
    float* __restrict__ out)
{
    __shared__ unsigned short aJ[256 * LPAD];
    __shared__ unsigned short bR[64 * LPAD];
    const int t = threadIdx.x;
    const int r0 = blockIdx.x * 64;
    const int w = t >> 6, lane = t & 63, quad = lane >> 4, l15 = lane & 15;

    floatx4 acc[4][4];
#pragma unroll
    for (int i = 0; i < 4; ++i)
#pragma unroll
        for (int j = 0; j < 4; ++j) acc[i][j] = (floatx4){0.f, 0.f, 0.f, 0.f};

    for (int k0 = 0; k0 < 256; k0 += 32) {
        __syncthreads();
        for (int i = 0; i < 4; ++i) {  // A: woT 256 rows x 32k = 1024 uint4
            int idx = i * 256 + t; int j = idx >> 2, kq = idx & 3;
            uint4 v = *(const uint4*)&wo[(long)j * 256 + k0 + 8 * kq];
            *(uint4*)&aJ[j * LPAD + 8 * kq] = v;
        }
        {   // B: preb 64 rows x 32k = 256 uint4
            int rr = t >> 2, kq = t & 3;
            uint4 v = *(const uint4*)&preb[(long)(r0 + rr) * 256 + k0 + 8 * kq];
            *(uint4*)&bR[rr * LPAD + 8 * kq] = v;
        }
        __syncthreads();
        short8_t am[4];
#pragma unroll
        for (int mi = 0; mi < 4; ++mi)
            am[mi] = *(const short8_t*)&aJ[(64 * w + 16 * mi + l15) * LPAD + 8 * quad];
#pragma unroll
        for (int nj = 0; nj < 4; ++nj) {
            short8_t b8 = *(const short8_t*)&bR[(16 * nj + l15) * LPAD + 8 * quad];
#pragma unroll
            for (int mi = 0; mi < 4; ++mi)
                acc[mi][nj] = MFMA16(am[mi], b8, acc[mi][nj]);
        }
    }

#pragma unroll
    for (int mi = 0; mi < 4; ++mi) {
        int j0 = 64 * w + 16 * mi + 4 * quad;
        float4 bias = *(const float4*)&b_out[j0];
#pragma unroll
        for (int nj = 0; nj < 4; ++nj) {
            int r = r0 + 16 * nj + l15;
            float4 res;
            res.x = acc[mi][nj][0] + bias.x;
            res.y = acc[mi][nj][1] + bias.y;
            res.z = acc[mi][nj][2] + bias.z;
            res.w = acc[mi][nj][3] + bias.w;
            *(float4*)&out[(long)r * 256 + j0] = res;
        }
    }
}

extern "C" void kernel_launch(void* const* d_in, const int* in_sizes, int n_in,
                              void* d_out, int out_size, void* d_ws, size_t ws_size,
                              hipStream_t stream) {
    const float* query  = (const float*)d_in[0];
    const float* refp   = (const float*)d_in[1];
    const float* feat0  = (const float*)d_in[2];
    const float* feat1  = (const float*)d_in[3];
    const float* feat2  = (const float*)d_in[4];
    const float* feat3  = (const float*)d_in[5];
    const float* W_off  = (const float*)d_in[6];
    const float* b_off  = (const float*)d_in[7];
    const float* W_attn = (const float*)d_in[8];
    const float* b_attn = (const float*)d_in[9];
    const float* Wv0 = (const float*)d_in[10]; const float* bv0 = (const float*)d_in[11];
    const float* Wv1 = (const float*)d_in[12]; const float* bv1 = (const float*)d_in[13];
    const float* Wv2 = (const float*)d_in[14]; const float* bv2 = (const float*)d_in[15];
    const float* Wv3 = (const float*)d_in[16]; const float* bv3 = (const float*)d_in[17];
    const float* W_out = (const float*)d_in[18]; const float* b_out = (const float*)d_in[19];
    float* out = (float*)d_out;

    char* ws = (char*)d_ws;
    uint2*          sinfo = (uint2*)(ws + 0);
    uint4*          guard_lo = (uint4*)(ws + 33554432);
    unsigned short* vbuf = (unsigned short*)(ws + 33685504);
    float*          gout = (float*)(ws + 33685504);   // overlaps vbuf (dead until vproj)
    uint4*          guard_hi = (uint4*)(ws + 122814464);
    unsigned short* preb = (unsigned short*)(ws + 122945536);
    unsigned short* wq   = (unsigned short*)(ws + 139722752);
    unsigned short* wv   = (unsigned short*)(ws + 139919360);
    unsigned short* wo   = (unsigned short*)(ws + 140443648);

    prep_kernel<<<64, 256, 0, stream>>>(W_off, W_attn, Wv0, Wv1, Wv2, Wv3, W_out,
                                        wq, wv, wo, guard_lo, guard_hi);
    qproj_gemm<<<512, 256, 0, stream>>>(query, wq, gout);
    setup_kernel<<<1024, 256, 0, stream>>>(gout, refp, b_off, b_attn, sinfo);
    vproj_mfma<<<2720, 256, 0, stream>>>(feat0, feat1, feat2, feat3, wv,
                                         bv0, bv1, bv2, bv3, vbuf);
    sample_kernel<<<8192, 256, 0, stream>>>(sinfo, vbuf, preb);
    outproj_mfma<<<512, 256, 0, stream>>>(preb, wo, b_out, out);
}